// Round 1
// 13.413 us; speedup vs baseline: 1.3384x; 1.3384x over previous
//
#include <hip/hip_runtime.h>
#include <hip/hip_bf16.h>
#include <stdint.h>

#define NPTS 8192
#define DIM  64
#define NB   4
#define KK   9
#define BQ   64       // queries per block
#define RROWS 160     // staged rows: global m = n0-89+r, r in [0,159]; rows [0,152] used
#define SD2  72       // stage row stride in bf16 elems (144 B, 16B-aligned rows)
#define UD   65       // key-matrix row stride in uints (odd -> bank = (r+q)%32)

typedef short bf16x8 __attribute__((ext_vector_type(8)));
typedef float f32x4  __attribute__((ext_vector_type(4)));

// BQ=64 fused KNN: stage bf16 (transpose) + f32 norm partials -> banded MFMA Gram
// (4 qtiles x 7 rtiles each) -> packed 32-bit keys -> 8-lane/query top-9 extraction.
// Query q (global n = n0+q) is staged row q+89; candidate m = n-89+wofs is row q+wofs.
__global__ __launch_bounds__(512, 4) void knn_fused(const float* __restrict__ x,
                                                    int* __restrict__ out) {
    __shared__ uint32_t ud[RROWS * UD];   // 41600 B keys; first 4 KB doubles as psum
    __shared__ ushort   sb[RROWS * SD2];  // 23040 B staged bf16
    __shared__ float    rnArr[RROWS];     // 640 B inverse norms

    float* psumA = (float*)ud;            // [512] partials rows 0..127
    float* psumB = (float*)ud + 512;      // [512] partials rows 128..159

    const int tid = threadIdx.x;
    // XCD-chunked swizzle: blocks on the same XCD (blk%8) get consecutive tiles,
    // so the 96-row window overlap between neighbors hits that XCD's L2.
    const int blk = blockIdx.x;
    const int L   = (blk & 7) * 64 + (blk >> 3);   // 512 blocks, bijective
    const int b   = L >> 7;                        // 128 tiles per batch
    const int n0  = (L & 127) << 6;
    const int gbase = n0 - 89;

    const float* xb = x + (size_t)b * DIM * NPTS;

    // ---- stage region 1: rows 0..127, 4 threads/row x 16 dims ----
    {
        const int g  = tid & 127;
        const int dh = (tid >> 7) << 4;            // 0,16,32,48
        const int gg = gbase + g;
        const bool ok = (gg >= 0 && gg < NPTS);
        const float* src = xb + (ok ? gg : 0);
        float s = 0.f;
#pragma unroll
        for (int j = 0; j < 2; ++j) {
            uint32_t pk[4];
#pragma unroll
            for (int e = 0; e < 4; ++e) {
                int d = dh + j * 8 + e * 2;
                float v0 = ok ? src[(size_t)d * NPTS] : 0.f;
                float v1 = ok ? src[(size_t)(d + 1) * NPTS] : 0.f;
                s += v0 * v0 + v1 * v1;
                __hip_bfloat162 h2 = __float22bfloat162_rn(make_float2(v0, v1));
                pk[e] = *reinterpret_cast<uint32_t*>(&h2);
            }
            *reinterpret_cast<uint4*>(&sb[(size_t)g * SD2 + dh + j * 8]) =
                make_uint4(pk[0], pk[1], pk[2], pk[3]);
        }
        psumA[tid] = s;
    }
    // ---- stage region 2: rows 128..159, 16 threads/row x 4 dims ----
    {
        const int g  = 128 + (tid & 31);
        const int c  = tid >> 5;                   // 0..15
        const int gg = gbase + g;
        const bool ok = (gg >= 0 && gg < NPTS);
        const float* src = xb + (ok ? gg : 0);
        float s = 0.f;
        uint32_t pk[2];
#pragma unroll
        for (int e = 0; e < 2; ++e) {
            int d = c * 4 + e * 2;
            float v0 = ok ? src[(size_t)d * NPTS] : 0.f;
            float v1 = ok ? src[(size_t)(d + 1) * NPTS] : 0.f;
            s += v0 * v0 + v1 * v1;
            __hip_bfloat162 h2 = __float22bfloat162_rn(make_float2(v0, v1));
            pk[e] = *reinterpret_cast<uint32_t*>(&h2);
        }
        *reinterpret_cast<uint2*>(&sb[(size_t)g * SD2 + c * 4]) = make_uint2(pk[0], pk[1]);
        psumB[tid] = s;
    }
    __syncthreads();   // bar1: sb + psum visible

    // ---- frag loads (sb) overlapped with inverse-norm computation ----
    const int w  = tid >> 6;
    const int l  = tid & 63;
    const int qt = w >> 1;            // query tile 0..3
    const int h  = w & 1;             // row-tile half: h=0 -> rto 0..3, h=1 -> rto 4..6
    const int lr = l & 15;
    const int lk = l >> 4;
    const int nrt = 4 - h;            // 4 or 3 row tiles (band: rows 16qt .. 16qt+111)

    const ushort* ap = &sb[(size_t)(89 + qt * 16 + lr) * SD2 + lk * 8];
    bf16x8 a0 = *reinterpret_cast<const bf16x8*>(ap);
    bf16x8 a1 = *reinterpret_cast<const bf16x8*>(ap + 32);
    bf16x8 bfr[4][2];
#pragma unroll
    for (int i = 0; i < 4; ++i) {
        if (i < nrt) {
            const int rto = h * 4 + i;
            const ushort* bp = &sb[(size_t)(qt * 16 + rto * 16 + lr) * SD2 + lk * 8];
            bfr[i][0] = *reinterpret_cast<const bf16x8*>(bp);
            bfr[i][1] = *reinterpret_cast<const bf16x8*>(bp + 32);
        }
    }

    if (tid < 128) {
        float s = psumA[tid] + psumA[tid + 128] + psumA[tid + 256] + psumA[tid + 384];
        rnArr[tid] = 1.0f / fmaxf(sqrtf(s), 1e-12f);
    } else if (tid < 160) {
        int rr = tid - 128;
        float s = 0.f;
#pragma unroll
        for (int k = 0; k < 16; ++k) s += psumB[rr + 32 * k];
        rnArr[tid] = 1.0f / fmaxf(sqrtf(s), 1e-12f);
    }
    __syncthreads();   // bar2: rnArr visible; psum dead (ud may be overwritten now)

    // ---- MFMA + key pack/write: ud[r][q] = mono(dist)&~127 | (r-q) ----
    {
        float rq[4];
#pragma unroll
        for (int j = 0; j < 4; ++j) rq[j] = rnArr[89 + qt * 16 + lk * 4 + j];
        const int q0 = qt * 16 + lk * 4;
#pragma unroll
        for (int i = 0; i < 4; ++i) {
            if (i < nrt) {
                f32x4 acc = {0.f, 0.f, 0.f, 0.f};
                acc = __builtin_amdgcn_mfma_f32_16x16x32_bf16(a0, bfr[i][0], acc, 0, 0, 0);
                acc = __builtin_amdgcn_mfma_f32_16x16x32_bf16(a1, bfr[i][1], acc, 0, 0, 0);
                const int rto = h * 4 + i;
                const int r = qt * 16 + rto * 16 + lr;
                const float rnr = rnArr[r];
#pragma unroll
                for (int j = 0; j < 4; ++j) {
                    float p = acc[j] * rq[j] * rnr;
                    float dist = 2.0f - 2.0f * p;
                    uint32_t uu = __float_as_uint(dist);
                    uu = (uu & 0x80000000u) ? ~uu : (uu | 0x80000000u);
                    int rel = r - (q0 + j);          // window offset, in [0,89] where read
                    ud[r * UD + q0 + j] = (uu & 0xFFFFFF80u) | ((uint32_t)rel & 127u);
                }
            }
        }
    }
    __syncthreads();   // bar3

    // ---- selection: 8 lanes per query, 9 rounds of masked-min extraction ----
    {
        const int ql = l >> 3;             // 0..7
        const int s  = l & 7;              // 0..7
        const int q  = (w << 3) | ql;      // 0..63
        const int n  = n0 + q;

        uint32_t key[12];
#pragma unroll
        for (int t = 0; t < 12; ++t) {
            int wofs = s + 8 * t;          // window offset 0..95
            int m = n - 89 + wofs;
            bool ok = (wofs <= 89) && (m >= 0);
            int r = q + (ok ? wofs : 0);
            uint32_t raw = ud[r * UD + q];
            key[t] = ok ? raw : 0xFFFFFFFFu;
        }

        uint32_t prev = 0;
        int omKeep = n;
        int om8 = n;
#pragma unroll
        for (int j = 0; j < KK; ++j) {
            uint32_t mn = 0xFFFFFFFFu;
#pragma unroll
            for (int t = 0; t < 12; ++t) {
                uint32_t cand = (key[t] > prev) ? key[t] : 0xFFFFFFFFu;
                mn = (cand < mn) ? cand : mn;
            }
            uint32_t o;
            o = (uint32_t)__shfl_xor((int)mn, 1); mn = (o < mn) ? o : mn;
            o = (uint32_t)__shfl_xor((int)mn, 2); mn = (o < mn) ? o : mn;
            o = (uint32_t)__shfl_xor((int)mn, 4); mn = (o < mn) ? o : mn;
            int om = (mn == 0xFFFFFFFFu) ? n : (n - 89 + (int)(mn & 127u));
            if (j < 8) {
                if (s == j) omKeep = om;
            } else {
                om8 = om;
            }
            prev = mn;
        }

        const int base0 = (b * NPTS + n) * KK;
        const int base1 = NB * NPTS * KK + base0;
        out[base0 + s] = omKeep;           // 8 coalesced lanes per query
        out[base1 + s] = n;
        if (s == 0) {
            out[base0 + 8] = om8;
            out[base1 + 8] = n;
        }
    }
}

extern "C" void kernel_launch(void* const* d_in, const int* in_sizes, int n_in,
                              void* d_out, int out_size, void* d_ws, size_t ws_size,
                              hipStream_t stream) {
    const float* x = (const float*)d_in[0];
    int* out = (int*)d_out;
    knn_fused<<<NB * (NPTS / BQ), 512, 0, stream>>>(x, out);
}